// Round 1
// baseline (125.536 us; speedup 1.0000x reference)
//
#include <hip/hip_runtime.h>
#include <math.h>

// Perona-Malik (option 2) fused stencil for x:[B,1,H,W] fp32, H=W=1024.
//
// Reference decomposition (all convs are 2-point diffs, reflect padding):
//   fx(i,j) = c*(x[i,jp]-x[i,j]),  jp = (j+1<W)? j+1 : W-2
//   fy(i,j) = c*(x[im,j]-x[i,j]),  im = (i>=1)? i-1 : 1
//   cI = exp(-(fx^2+fy^2)/900);  g = fx*cI;  h = fy*cI
//   term(i,j) = c*(g(i,j)-g(i,jm)) + c*(h(i,j)-h(ip,j))
//     jm = (j>=1)? j-1 : 1 ;  ip = (i+1<H)? i+1 : H-2
// g/h are reflected AFTER being computed on the real grid, so boundary taps
// are real g/h samples (g(i,1) at j=0; h(H-2,j) at i=H-1 -> needs row H-3).

#define HH 1024
#define WW 1024

__device__ __forceinline__ void gh_eval(float xc, float xr, float xu,
                                        float& g, float& h) {
    const float c = 0.70710678118654752f;   // 1/sqrt(2)
    float fx = c * (xr - xc);
    float fy = c * (xu - xc);
    float cI = __expf(-(fx * fx + fy * fy) * (1.0f / 900.0f));
    g = fx * cI;
    h = fy * cI;
}

__global__ __launch_bounds__(256)
void pm_kernel(const float* __restrict__ x, float* __restrict__ out) {
    const int H = HH, W = WW;
    const int i = blockIdx.x;          // row
    const int b = blockIdx.y;          // batch
    const float* xb = x + (size_t)b * H * W;
    float*       ob = out + (size_t)b * H * W;
    const int j0 = threadIdx.x << 2;   // 4 pixels per thread

    const int rm = (i >= 1)    ? i - 1 : 1;       // reflect(i-1)
    const int rp = (i + 1 < H) ? i + 1 : H - 2;   // reflect(i+1)
    const int rq = rp - 1;                        // reflect(rp-1); rp>=1 always

    // Coalesced float4 row loads
    const float4 xrC = *(const float4*)(xb + (size_t)i  * W + j0);
    const float4 xmC = *(const float4*)(xb + (size_t)rm * W + j0);
    const float4 xpC = *(const float4*)(xb + (size_t)rp * W + j0);
    const float4 xqC = *(const float4*)(xb + (size_t)rq * W + j0);

    // Edge scalars (column reflections folded in)
    const int cl = (j0 >= 1)     ? j0 - 1 : 1;      // reflect(j0-1)
    const int cr = (j0 + 4 < W)  ? j0 + 4 : W - 2;  // reflect(j0+4)
    const float xr_l = xb[(size_t)i  * W + cl];
    const float xr_r = xb[(size_t)i  * W + cr];
    const float xm_l = xb[(size_t)rm * W + cl];
    const float xp_r = xb[(size_t)rp * W + cr];

    // Register windows: xr = row i cols [j0-1 .. j0+4]; xm = row rm [j0-1 .. j0+3]
    //                   xp = row rp cols [j0 .. j0+4]; xq = row rq [j0 .. j0+3]
    float xr[6] = {xr_l, xrC.x, xrC.y, xrC.z, xrC.w, xr_r};
    float xm[5] = {xm_l, xmC.x, xmC.y, xmC.z, xmC.w};
    float xp[5] = {xpC.x, xpC.y, xpC.z, xpC.w, xp_r};
    float xq[4] = {xqC.x, xqC.y, xqC.z, xqC.w};

    float gC[4], hC[4], hP[4];
#pragma unroll
    for (int k = 0; k < 4; ++k) {
        // g,h at (i, j0+k):    xright = x(i, j0+k+1) (k=3 uses reflected xr_r)
        gh_eval(xr[k + 1], xr[k + 2], xm[k + 1], gC[k], hC[k]);
        // h at (rp, j0+k):     fx from row rp, fy uses row rq = reflect(rp-1)
        float gdum;
        gh_eval(xp[k], xp[k + 1], xq[k], gdum, hP[k]);
    }

    // Left-neighbor g: g(i, jm(j0)).  j0==0 -> jm=1 -> reuse gC[1] (real sample).
    float gL;
    if (j0 == 0) {
        gL = gC[1];
    } else {
        float hdum;
        gh_eval(xr[0], xr[1], xm[0], gL, hdum);
    }

    const float c = 0.70710678118654752f;
    float4 o;
    o.x = c * ((gC[0] - gL)    + (hC[0] - hP[0]));
    o.y = c * ((gC[1] - gC[0]) + (hC[1] - hP[1]));
    o.z = c * ((gC[2] - gC[1]) + (hC[2] - hP[2]));
    o.w = c * ((gC[3] - gC[2]) + (hC[3] - hP[3]));
    *(float4*)(ob + (size_t)i * W + j0) = o;
}

extern "C" void kernel_launch(void* const* d_in, const int* in_sizes, int n_in,
                              void* d_out, int out_size, void* d_ws, size_t ws_size,
                              hipStream_t stream) {
    const float* x = (const float*)d_in[0];
    float* out = (float*)d_out;
    const int total = in_sizes[0];
    const int B = total / (HH * WW);       // 16
    dim3 grid(HH, B);                      // one row per block
    pm_kernel<<<grid, 256, 0, stream>>>(x, out);
}

// Round 3
// 111.196 us; speedup vs baseline: 1.1290x; 1.1290x over previous
//
#include <hip/hip_runtime.h>
#include <math.h>

// Perona-Malik (option 2) fused stencil, x:[B,1,H,W] fp32, H=W=1024.
//
//   fx(i,j) = c*(x[i,jp]-x[i,j]),  jp = (j+1<W)? j+1 : W-2
//   fy(i,j) = c*(x[im,j]-x[i,j]),  im = (i>=1)? i-1 : 1
//   cI = exp(-(fx^2+fy^2)/900);  g = fx*cI;  h = fy*cI
//   out(i,j) = c*(g(i,j)-g(i,jm)) + c*(h(i,j)-h(ip,j))
//     jm = (j>=1)? j-1 : 1 ;  ip = (i+1<H)? i+1 : H-2
//
// Rolling-row structure: each block owns an RR-row tile and sweeps down.
// Per iteration: load ONE new row, eval (g,h) once, emit previous row.
// Reads = RR+2 rows per RR output rows (1.25x at RR=8) vs 3x for the
// one-row-per-block version.

#define HH 1024
#define WW 1024
#define RR 8

typedef float vfloat4 __attribute__((ext_vector_type(4)));  // native vec for nontemporal store

__device__ __forceinline__ void gh_eval(float xc, float xr, float xu,
                                        float& g, float& h) {
    const float c = 0.70710678118654752f;   // 1/sqrt(2)
    float fx = c * (xr - xc);
    float fy = c * (xu - xc);
    float cI = __expf(-(fx * fx + fy * fy) * (1.0f / 900.0f));
    g = fx * cI;
    h = fy * cI;
}

__device__ __forceinline__ void store_nt4(float* p, float a, float b, float cc, float d) {
    vfloat4 v = {a, b, cc, d};
    __builtin_nontemporal_store(v, (vfloat4*)p);
}

__global__ __launch_bounds__(256)
void pm_kernel(const float* __restrict__ x, float* __restrict__ out) {
    const int H = HH, W = WW;
    const int r0 = blockIdx.x * RR;       // first output row of this tile
    const int b  = blockIdx.y;
    const float* xb = x + (size_t)b * H * W;
    float*       ob = out + (size_t)b * H * W;
    const int j0 = threadIdx.x << 2;      // 4 pixels/thread
    const int cl = (j0 >= 1)    ? j0 - 1 : 1;      // reflect(j0-1)
    const int cr = (j0 + 4 < W) ? j0 + 4 : W - 2;  // reflect(j0+4)
    const float c = 0.70710678118654752f;

    // ---- prologue: row above (reflected) + first tile row ----
    float xm[5], xr[6];
    {
        const int pm = (r0 >= 1) ? r0 - 1 : 1;     // reflect(r0-1)
        const float4 vm = *(const float4*)(xb + (size_t)pm * W + j0);
        xm[0] = xb[(size_t)pm * W + cl];
        xm[1] = vm.x; xm[2] = vm.y; xm[3] = vm.z; xm[4] = vm.w;

        const float4 vr = *(const float4*)(xb + (size_t)r0 * W + j0);
        xr[0] = xb[(size_t)r0 * W + cl];
        xr[1] = vr.x; xr[2] = vr.y; xr[3] = vr.z; xr[4] = vr.w;
        xr[5] = xb[(size_t)r0 * W + cr];
    }

    // (g,h) for row r0: gw covers cols j0-1..j0+3, hc covers j0..j0+3
    float gw[5], hc[4], hprev[4];
#pragma unroll
    for (int t = 0; t < 5; ++t) {
        float g, h;
        gh_eval(xr[t], xr[t + 1], xm[t], g, h);
        gw[t] = g;
        if (t >= 1) hc[t - 1] = h;
    }
    if (j0 == 0) gw[0] = gw[2];           // jm(0)=1 -> g(i,1)

    // ---- body: rows r0 .. r0+RR-2 always have a next row in-bounds ----
#pragma unroll
    for (int k = 0; k < RR - 1; ++k) {
        const int r = r0 + k;
        // load row r+1 (6-wide window), eval its (g,h) using row r as "up"
        float xn[6];
        {
            const size_t base = (size_t)(r + 1) * W;
            const float4 v = *(const float4*)(xb + base + j0);
            xn[0] = xb[base + cl];
            xn[1] = v.x; xn[2] = v.y; xn[3] = v.z; xn[4] = v.w;
            xn[5] = xb[base + cr];
        }
        float gw2[5], hn[4];
#pragma unroll
        for (int t = 0; t < 5; ++t) {
            float g, h;
            gh_eval(xn[t], xn[t + 1], xr[t], g, h);
            gw2[t] = g;
            if (t >= 1) hn[t - 1] = h;
        }
        if (j0 == 0) gw2[0] = gw2[2];

        store_nt4(ob + (size_t)r * W + j0,
                  c * ((gw[1] - gw[0]) + (hc[0] - hn[0])),
                  c * ((gw[2] - gw[1]) + (hc[1] - hn[1])),
                  c * ((gw[3] - gw[2]) + (hc[2] - hn[2])),
                  c * ((gw[4] - gw[3]) + (hc[3] - hn[3])));

        // shift state down one row
#pragma unroll
        for (int t = 0; t < 6; ++t) xr[t] = xn[t];
#pragma unroll
        for (int t = 0; t < 5; ++t) gw[t] = gw2[t];
#pragma unroll
        for (int t = 0; t < 4; ++t) { hprev[t] = hc[t]; hc[t] = hn[t]; }
    }

    // ---- epilogue row rL = r0+RR-1 ----
    {
        const int rL = r0 + RR - 1;
        float hP[4];
        if (rL + 1 < H) {                  // interior tile: load the halo row
            float xn[6];
            const size_t base = (size_t)(rL + 1) * W;
            const float4 v = *(const float4*)(xb + base + j0);
            xn[0] = xb[base + cl];
            xn[1] = v.x; xn[2] = v.y; xn[3] = v.z; xn[4] = v.w;
            xn[5] = xb[base + cr];
#pragma unroll
            for (int t = 1; t < 5; ++t) {  // only h needed (cols j0..j0+3)
                float g, h;
                gh_eval(xn[t], xn[t + 1], xr[t], g, h);
                hP[t - 1] = h;
            }
        } else {                           // rL = H-1: ip reflects to H-2
            hP[0] = hprev[0]; hP[1] = hprev[1];
            hP[2] = hprev[2]; hP[3] = hprev[3];
        }
        store_nt4(ob + (size_t)rL * W + j0,
                  c * ((gw[1] - gw[0]) + (hc[0] - hP[0])),
                  c * ((gw[2] - gw[1]) + (hc[1] - hP[1])),
                  c * ((gw[3] - gw[2]) + (hc[2] - hP[2])),
                  c * ((gw[4] - gw[3]) + (hc[3] - hP[3])));
    }
}

extern "C" void kernel_launch(void* const* d_in, const int* in_sizes, int n_in,
                              void* d_out, int out_size, void* d_ws, size_t ws_size,
                              hipStream_t stream) {
    const float* x = (const float*)d_in[0];
    float* out = (float*)d_out;
    const int total = in_sizes[0];
    const int B = total / (HH * WW);       // 16
    dim3 grid(HH / RR, B);                 // 8-row tile per block
    pm_kernel<<<grid, 256, 0, stream>>>(x, out);
}